// Round 5
// baseline (66.980 us; speedup 1.0000x reference)
//
#include <hip/hip_runtime.h>
#include <stdint.h>

#define B_ 4
#define N_ 4096
#define Q_ 4096
#define K_ 32
#define E_ 32
#define R_ 16
#define F_ 53   // 3 rel_pos + 1 radius + 32 emb + 16 rbf + 1 dist

static constexpr int WAVES   = 16;          // waves per block
static constexpr int THREADS = WAVES * 64;  // 1024
static constexpr int QPB     = 32;          // 2 queries per wave
static constexpr int CAP     = 104;         // per-query candidate capacity (u64)
static constexpr int TILE    = K_ * F_;     // 1696 floats per query tile
static constexpr int NSLOT   = 4;           // stage slots time-shared by waves
static constexpr int POOLB   = (QPB * CAP * 8 > NSLOT * TILE * 4)
                             ? (QPB * CAP * 8) : (NSLOT * TILE * 4);

__device__ __forceinline__ unsigned int s2bits(float qx, float qy, float qz,
                                               float cx, float cy, float cz) {
    // bit-exact reference ordering: no FMA, fixed association, NO eps here
    const float dx = __fsub_rn(qx, cx);
    const float dy = __fsub_rn(qy, cy);
    const float dz = __fsub_rn(qz, cz);
    return __float_as_uint(
        __fadd_rn(__fadd_rn(__fmul_rn(dx, dx), __fmul_rn(dy, dy)),
                  __fmul_rn(dz, dz)));
}

// conservative s-bits threshold covering every atom with d <= sqrt(Ts+eps)
__device__ __forceinline__ unsigned int sbits_threshold(unsigned int Ts) {
    const float dT = __fsqrt_rn(__fadd_rn(__uint_as_float(Ts), 1e-12f));
    const float u  = __uint_as_float(__float_as_uint(dT) + 1);   // next float up
    unsigned int ST = __float_as_uint(__fmul_rn(u, u)) + 2;
    return ST < Ts ? Ts : ST;   // degenerate (inf/NaN) floods -> fallback
}

__device__ __forceinline__ void bitonic_sort64_u32(unsigned int& v, int lane) {
    #pragma unroll
    for (int k = 2; k <= 64; k <<= 1) {
        #pragma unroll
        for (int j = k >> 1; j > 0; j >>= 1) {
            unsigned int o = __shfl_xor(v, j);
            const bool asc = ((lane & k) == 0);
            const bool lower = ((lane & j) == 0);
            unsigned int mn = v < o ? v : o;
            unsigned int mx = v < o ? o : v;
            v = (lower == asc) ? mn : mx;
        }
    }
}

__device__ __forceinline__ void bitonic_sort64_u64(unsigned long long& v, int lane) {
    #pragma unroll
    for (int k = 2; k <= 64; k <<= 1) {
        #pragma unroll
        for (int j = k >> 1; j > 0; j >>= 1) {
            unsigned long long o = __shfl_xor(v, j);
            const bool asc = ((lane & k) == 0);
            const bool lower = ((lane & j) == 0);
            unsigned long long mn = v < o ? v : o;
            unsigned long long mx = v < o ? o : v;
            v = (lower == asc) ? mn : mx;
        }
    }
}

// merge sorted-asc `best` with sorted-asc `c` (both 64-wide), keep lowest 64 sorted
__device__ __forceinline__ void merge64_u64(unsigned long long& best,
                                            unsigned long long c, int lane) {
    unsigned long long rev = __shfl(c, 63 - lane);
    unsigned long long v = best < rev ? best : rev;
    #pragma unroll
    for (int j = 32; j > 0; j >>= 1) {
        unsigned long long o = __shfl_xor(v, j);
        const bool lower = ((lane & j) == 0);
        unsigned long long mn = v < o ? v : o;
        unsigned long long mx = v < o ? o : v;
        v = lower ? mn : mx;
    }
    best = v;
}

__global__ __launch_bounds__(THREADS, 8)
void lfb_kernel(const float* __restrict__ coords,
                const int* __restrict__ atom_types,
                const float* __restrict__ radii,
                const float* __restrict__ qpts,
                const int* __restrict__ atom_mask,
                const int* __restrict__ query_mask,
                const float* __restrict__ embed,
                const float* __restrict__ centers,
                float* __restrict__ out)
{
    __shared__ __align__(16) float sx[N_], sy[N_], sz[N_];
    __shared__ __align__(16) unsigned char pool[POOLB]; // cand bufs / stage slots
    __shared__ int wcnt[QPB];

    const int tid  = threadIdx.x;
    const int lane = tid & 63;
    const int wv   = tid >> 6;
    const int bq0  = blockIdx.x * QPB;
    const int b    = bq0 / Q_;          // Q_ % QPB == 0: one batch per block

    // stage coords; masked atoms poisoned to 1e30 -> s == +inf bit-exactly
    for (int i = tid; i < N_; i += THREADS) {
        const float* c = coords + (size_t)(b * N_ + i) * 3;
        const bool mv = atom_mask[b * N_ + i] != 0;
        sx[i] = mv ? c[0] : 1e30f;
        sy[i] = mv ? c[1] : 1e30f;
        sz[i] = mv ? c[2] : 1e30f;
    }
    if (tid < QPB) wcnt[tid] = 0;
    __syncthreads();

    const int qA = bq0 + wv;            // this wave's two queries
    const int qB = bq0 + WAVES + wv;
    const float qxA = qpts[(size_t)qA * 3 + 0];
    const float qyA = qpts[(size_t)qA * 3 + 1];
    const float qzA = qpts[(size_t)qA * 3 + 2];
    const float qxB = qpts[(size_t)qB * 3 + 0];
    const float qyB = qpts[(size_t)qB * 3 + 1];
    const float qzB = qpts[(size_t)qB * 3 + 2];

    // ---- pass 1: per-lane min of raw squared-dist bits, BOTH queries per read ----
    unsigned int mnA = 0xFFFFFFFFu, mnB = 0xFFFFFFFFu;
    for (int i = 0; i < N_ / 256; ++i) {
        const int a0 = i * 256 + lane * 4;
        const float4 X = *(const float4*)&sx[a0];
        const float4 Y = *(const float4*)&sy[a0];
        const float4 Z = *(const float4*)&sz[a0];
        unsigned int a0b = s2bits(qxA, qyA, qzA, X.x, Y.x, Z.x);
        unsigned int a1b = s2bits(qxA, qyA, qzA, X.y, Y.y, Z.y);
        unsigned int a2b = s2bits(qxA, qyA, qzA, X.z, Y.z, Z.z);
        unsigned int a3b = s2bits(qxA, qyA, qzA, X.w, Y.w, Z.w);
        unsigned int b0b = s2bits(qxB, qyB, qzB, X.x, Y.x, Z.x);
        unsigned int b1b = s2bits(qxB, qyB, qzB, X.y, Y.y, Z.y);
        unsigned int b2b = s2bits(qxB, qyB, qzB, X.z, Y.z, Z.z);
        unsigned int b3b = s2bits(qxB, qyB, qzB, X.w, Y.w, Z.w);
        unsigned int ma = (a0b < a1b ? a0b : a1b);
        unsigned int mb = (a2b < a3b ? a2b : a3b);
        ma = ma < mb ? ma : mb;
        mnA = mnA < ma ? mnA : ma;
        unsigned int na = (b0b < b1b ? b0b : b1b);
        unsigned int nb = (b2b < b3b ? b2b : b3b);
        na = na < nb ? na : nb;
        mnB = mnB < na ? mnB : na;
    }
    bitonic_sort64_u32(mnA, lane);
    bitonic_sort64_u32(mnB, lane);
    const unsigned int STA = sbits_threshold(__shfl(mnA, 31));
    const unsigned int STB = sbits_threshold(__shfl(mnB, 31));

    // ---- pass 2: collect candidates for both queries from one coord read ----
    unsigned long long* cb = reinterpret_cast<unsigned long long*>(pool);
    unsigned long long* cbA = cb + (size_t)wv * CAP;
    unsigned long long* cbB = cb + (size_t)(WAVES + wv) * CAP;
    int* cntAp = &wcnt[wv];
    int* cntBp = &wcnt[WAVES + wv];
    for (int i = 0; i < N_ / 256; ++i) {
        const int a0 = i * 256 + lane * 4;
        const float4 X = *(const float4*)&sx[a0];
        const float4 Y = *(const float4*)&sy[a0];
        const float4 Z = *(const float4*)&sz[a0];
        unsigned int sA[4], sB[4];
        sA[0] = s2bits(qxA, qyA, qzA, X.x, Y.x, Z.x);
        sA[1] = s2bits(qxA, qyA, qzA, X.y, Y.y, Z.y);
        sA[2] = s2bits(qxA, qyA, qzA, X.z, Y.z, Z.z);
        sA[3] = s2bits(qxA, qyA, qzA, X.w, Y.w, Z.w);
        sB[0] = s2bits(qxB, qyB, qzB, X.x, Y.x, Z.x);
        sB[1] = s2bits(qxB, qyB, qzB, X.y, Y.y, Z.y);
        sB[2] = s2bits(qxB, qyB, qzB, X.z, Y.z, Z.z);
        sB[3] = s2bits(qxB, qyB, qzB, X.w, Y.w, Z.w);
        #pragma unroll
        for (int j = 0; j < 4; ++j) {
            if (sA[j] <= STA) {                       // rare (~1%/lane)
                const int slot = atomicAdd(cntAp, 1); // order-free buffer
                if (slot < CAP)
                    cbA[slot] = ((unsigned long long)sA[j] << 32)
                              | (unsigned int)(a0 + j);
            }
            if (sB[j] <= STB) {
                const int slot = atomicAdd(cntBp, 1);
                if (slot < CAP)
                    cbB[slot] = ((unsigned long long)sB[j] << 32)
                              | (unsigned int)(a0 + j);
            }
        }
    }
    // counters written only by this wave's lanes -> same-wave LDS ordering suffices
    const int cntA = *cntAp;
    const int cntB = *cntBp;

    // ---- pass 3 / fallback: exact (d_bits, idx) top-32 per query ----
    auto select_top32 = [&](const unsigned long long* cbuf, int cnt,
                            float qx, float qy, float qz) -> unsigned long long {
        if (cnt <= CAP) {
            unsigned long long best = ~0ull;
            const int nch = (cnt + 63) >> 6;
            for (int c = 0; c < nch; ++c) {
                const int slot = c * 64 + lane;
                unsigned long long v = ~0ull;
                if (slot < cnt) {
                    const unsigned long long raw = cbuf[slot];
                    const float s = __uint_as_float((unsigned int)(raw >> 32));
                    const float d = __fsqrt_rn(__fadd_rn(s, 1e-12f)); // ref path
                    v = ((unsigned long long)__float_as_uint(d) << 32)
                      | (unsigned int)(raw & 0xFFFFFFFFull);
                }
                bitonic_sort64_u64(v, lane);
                if (c == 0) best = v;
                else        merge64_u64(best, v, lane);
            }
            return best;
        }
        // fallback (pathological masks/ties): exact streaming insertion
        unsigned long long key = ~0ull;
        for (int base = 0; base < N_; base += 64) {
            const int a = base + lane;
            const unsigned int sb = s2bits(qx, qy, qz, sx[a], sy[a], sz[a]);
            const float d = __fsqrt_rn(__fadd_rn(__uint_as_float(sb), 1e-12f));
            unsigned long long cand =
                ((unsigned long long)__float_as_uint(d) << 32) | (unsigned int)a;
            const unsigned long long T = __shfl(key, 31);
            unsigned long long m = __ballot(cand < T);
            while (m) {
                const int src = __ffsll(m) - 1;
                m &= m - 1;
                const unsigned long long nk = __shfl(cand, src);
                const unsigned long long up = __shfl_up(key, 1);
                if (lane < K_) {
                    const unsigned long long repl =
                        (lane == 0) ? nk : (up <= nk ? nk : up);
                    key = (key <= nk) ? key : repl;
                }
            }
        }
        return key;
    };

    const unsigned long long keyA = select_top32(cbA, cntA, qxA, qyA, qzA);
    const unsigned long long keyB = select_top32(cbB, cntB, qxB, qyB, qzB);

    const size_t BQK = (size_t)B_ * Q_ * K_;
    float* out_feat = out;
    float* out_mask = out + BQK * (size_t)F_;
    float* out_idx  = out_mask + BQK;
    float* out_dist = out_idx + BQK;

    const bool qmA = query_mask[qA] != 0;
    const bool qmB = query_mask[qB] != 0;

    // scalar outputs (no stage pool needed) before the overlay barrier
    if (lane < K_) {
        {
            const float d = __uint_as_float((unsigned int)(keyA >> 32));
            const int  id = (int)(keyA & 0xFFFFFFFFull);
            const bool am = ((unsigned int)(keyA >> 32)) < 0x7F800000u;
            const bool nm = am && (d <= 5.0f) && qmA;
            const size_t o = (size_t)qA * K_ + lane;
            out_mask[o] = nm ? 1.0f : 0.0f;
            out_idx[o]  = am ? (float)id : -1.0f;
            out_dist[o] = nm ? d : 0.0f;
        }
        {
            const float d = __uint_as_float((unsigned int)(keyB >> 32));
            const int  id = (int)(keyB & 0xFFFFFFFFull);
            const bool am = ((unsigned int)(keyB >> 32)) < 0x7F800000u;
            const bool nm = am && (d <= 5.0f) && qmB;
            const size_t o = (size_t)qB * K_ + lane;
            out_mask[o] = nm ? 1.0f : 0.0f;
            out_idx[o]  = am ? (float)id : -1.0f;
            out_dist[o] = nm ? d : 0.0f;
        }
    }

    __syncthreads();   // all cand-buffer reads done before stage overlay

    // ---- feature build: NSLOT stage slots, 8 barrier rounds (2 per wave) ----
    auto build_and_store = [&](int q, unsigned long long key,
                               float qx, float qy, float qz, bool qm,
                               float* slotp) {
        const float d_l  = __uint_as_float((unsigned int)(key >> 32));
        const int   id_l = (int)(key & 0xFFFFFFFFull) & (N_ - 1);
        const bool  am_l = ((unsigned int)(key >> 32)) < 0x7F800000u;
        const bool  nm_l = am_l && (d_l <= 5.0f) && qm;

        if (lane < K_) {
            float* f = slotp + lane * F_;
            f[0] = nm_l ? __fsub_rn(qx, sx[id_l]) : 0.0f;
            f[1] = nm_l ? __fsub_rn(qy, sy[id_l]) : 0.0f;
            f[2] = nm_l ? __fsub_rn(qz, sz[id_l]) : 0.0f;
            f[3] = nm_l ? radii[b * N_ + id_l] : 0.0f;

            const int t = atom_types[b * N_ + id_l];
            const float4* er4 = (const float4*)(embed + t * E_);
            #pragma unroll
            for (int e = 0; e < E_ / 4; ++e) {
                const float4 v = er4[e];
                f[4 + e * 4 + 0] = nm_l ? v.x : 0.0f;
                f[4 + e * 4 + 1] = nm_l ? v.y : 0.0f;
                f[4 + e * 4 + 2] = nm_l ? v.z : 0.0f;
                f[4 + e * 4 + 3] = nm_l ? v.w : 0.0f;
            }

            const float NG = -(float)(256.0 / 25.0);   // -RBF_GAMMA
            #pragma unroll
            for (int rr = 0; rr < R_; ++rr) {
                const float dd = __fsub_rn(d_l, centers[rr]);
                const float a2 = __fmul_rn(dd, dd);
                f[36 + rr] = nm_l ? expf(__fmul_rn(NG, a2)) : 0.0f;
            }
            f[52] = nm_l ? d_l : 0.0f;
        }
        // same-wave LDS in-order: copy sees this wave's writes without a barrier
        const float4* s4 = (const float4*)slotp;
        float4* d4 = (float4*)(out_feat + (size_t)q * (size_t)TILE);
        for (int t4 = lane; t4 < TILE / 4; t4 += 64) d4[t4] = s4[t4];
    };

    float* stagef = reinterpret_cast<float*>(pool);
    for (int r = 0; r < 8; ++r) {
        if ((wv >> 2) == (r & 3)) {
            float* slotp = stagef + (size_t)(wv & (NSLOT - 1)) * TILE;
            if (r < 4) build_and_store(qA, keyA, qxA, qyA, qzA, qmA, slotp);
            else       build_and_store(qB, keyB, qxB, qyB, qzB, qmB, slotp);
        }
        __syncthreads();
    }
}

extern "C" void kernel_launch(void* const* d_in, const int* in_sizes, int n_in,
                              void* d_out, int out_size, void* d_ws, size_t ws_size,
                              hipStream_t stream) {
    const float* coords     = (const float*)d_in[0];
    const int*   atom_types = (const int*)d_in[1];
    const float* radii      = (const float*)d_in[2];
    const float* qpts       = (const float*)d_in[3];
    const int*   atom_mask  = (const int*)d_in[4];
    const int*   query_mask = (const int*)d_in[5];
    const float* embed      = (const float*)d_in[6];
    const float* centers    = (const float*)d_in[7];

    dim3 grid((B_ * Q_) / QPB);
    dim3 block(THREADS);
    lfb_kernel<<<grid, block, 0, stream>>>(coords, atom_types, radii, qpts,
                                           atom_mask, query_mask, embed, centers,
                                           (float*)d_out);
}

// Round 6
// 64.663 us; speedup vs baseline: 1.0358x; 1.0358x over previous
//
#include <hip/hip_runtime.h>
#include <stdint.h>

#define B_ 4
#define N_ 4096
#define Q_ 4096
#define K_ 32
#define E_ 32
#define R_ 16
#define F_ 53   // 3 rel_pos + 1 radius + 32 emb + 16 rbf + 1 dist

static constexpr int WAVES   = 16;          // waves per block
static constexpr int THREADS = WAVES * 64;  // 1024
static constexpr int QPB     = 32;          // 2 queries per wave
static constexpr int CAP     = 104;         // per-query candidate capacity (u32 idx)
static constexpr int TILE    = K_ * F_;     // 1696 floats per query tile
static constexpr int NSLOT   = 4;           // stage slots time-shared by waves
static constexpr int POOLB   = (QPB * CAP * 4 > NSLOT * TILE * 4)
                             ? (QPB * CAP * 4) : (NSLOT * TILE * 4);

typedef float v2f __attribute__((ext_vector_type(2)));

// VOP3P packed fp32 (CDNA2+): 2 FP32 ops per instruction
__device__ __forceinline__ v2f pk_add(v2f a, v2f b) {
    v2f d; asm("v_pk_add_f32 %0, %1, %2" : "=v"(d) : "v"(a), "v"(b)); return d;
}
__device__ __forceinline__ v2f pk_mul(v2f a, v2f b) {
    v2f d; asm("v_pk_mul_f32 %0, %1, %2" : "=v"(d) : "v"(a), "v"(b)); return d;
}
__device__ __forceinline__ v2f pk_fma(v2f a, v2f b, v2f c) {
    v2f d; asm("v_pk_fma_f32 %0, %1, %2, %3" : "=v"(d) : "v"(a), "v"(b), "v"(c)); return d;
}

// packed squared distance for 2 atoms: coords are pre-negated, so q + nc = q - c
__device__ __forceinline__ v2f pk_s2(v2f qx, v2f qy, v2f qz,
                                     v2f nx, v2f ny, v2f nz) {
    const v2f dx = pk_add(qx, nx);
    const v2f dy = pk_add(qy, ny);
    const v2f dz = pk_add(qz, nz);
    return pk_fma(dz, dz, pk_fma(dy, dy, pk_mul(dx, dx)));
}

__device__ __forceinline__ void bitonic_sort64_u32(unsigned int& v, int lane) {
    #pragma unroll
    for (int k = 2; k <= 64; k <<= 1) {
        #pragma unroll
        for (int j = k >> 1; j > 0; j >>= 1) {
            unsigned int o = __shfl_xor(v, j);
            const bool asc = ((lane & k) == 0);
            const bool lower = ((lane & j) == 0);
            unsigned int mn = v < o ? v : o;
            unsigned int mx = v < o ? o : v;
            v = (lower == asc) ? mn : mx;
        }
    }
}

__device__ __forceinline__ void bitonic_sort64_u64(unsigned long long& v, int lane) {
    #pragma unroll
    for (int k = 2; k <= 64; k <<= 1) {
        #pragma unroll
        for (int j = k >> 1; j > 0; j >>= 1) {
            unsigned long long o = __shfl_xor(v, j);
            const bool asc = ((lane & k) == 0);
            const bool lower = ((lane & j) == 0);
            unsigned long long mn = v < o ? v : o;
            unsigned long long mx = v < o ? o : v;
            v = (lower == asc) ? mn : mx;
        }
    }
}

// merge sorted-asc `best` with sorted-asc `c` (both 64-wide), keep lowest 64 sorted
__device__ __forceinline__ void merge64_u64(unsigned long long& best,
                                            unsigned long long c, int lane) {
    unsigned long long rev = __shfl(c, 63 - lane);
    unsigned long long v = best < rev ? best : rev;
    #pragma unroll
    for (int j = 32; j > 0; j >>= 1) {
        unsigned long long o = __shfl_xor(v, j);
        const bool lower = ((lane & j) == 0);
        unsigned long long mn = v < o ? v : o;
        unsigned long long mx = v < o ? o : v;
        v = lower ? mn : mx;
    }
    best = v;
}

__global__ __launch_bounds__(THREADS, 8)
void lfb_kernel(const float* __restrict__ coords,
                const int* __restrict__ atom_types,
                const float* __restrict__ radii,
                const float* __restrict__ qpts,
                const int* __restrict__ atom_mask,
                const int* __restrict__ query_mask,
                const float* __restrict__ embed,
                const float* __restrict__ centers,
                float* __restrict__ out)
{
    __shared__ __align__(16) float nsx[N_], nsy[N_], nsz[N_];  // NEGATED coords
    __shared__ __align__(16) unsigned char pool[POOLB];        // cand idx / stage

    const int tid  = threadIdx.x;
    const int lane = tid & 63;
    const int wv   = tid >> 6;
    const int bq0  = blockIdx.x * QPB;
    const int b    = bq0 / Q_;          // Q_ % QPB == 0: one batch per block

    // stage negated coords; masked atoms poisoned (-1e30 -> s == +inf bit-exactly)
    for (int i = tid; i < N_; i += THREADS) {
        const float* c = coords + (size_t)(b * N_ + i) * 3;
        const bool mv = atom_mask[b * N_ + i] != 0;
        nsx[i] = mv ? -c[0] : -1e30f;
        nsy[i] = mv ? -c[1] : -1e30f;
        nsz[i] = mv ? -c[2] : -1e30f;
    }
    __syncthreads();

    const int qA = bq0 + wv;            // this wave's two queries
    const int qB = bq0 + WAVES + wv;
    const float qxA = qpts[(size_t)qA * 3 + 0];
    const float qyA = qpts[(size_t)qA * 3 + 1];
    const float qzA = qpts[(size_t)qA * 3 + 2];
    const float qxB = qpts[(size_t)qB * 3 + 0];
    const float qyB = qpts[(size_t)qB * 3 + 1];
    const float qzB = qpts[(size_t)qB * 3 + 2];
    const v2f qxA2 = {qxA, qxA}, qyA2 = {qyA, qyA}, qzA2 = {qzA, qzA};
    const v2f qxB2 = {qxB, qxB}, qyB2 = {qyB, qyB}, qzB2 = {qzB, qzB};

    // ---- pass 1: per-lane min of packed-fma squared dist, both queries ----
    const float INF = __uint_as_float(0x7F800000u);
    float mA0 = INF, mA1 = INF, mB0 = INF, mB1 = INF;
    for (int i = 0; i < N_ / 256; ++i) {
        const int a0 = i * 256 + lane * 4;
        const float4 X = *(const float4*)&nsx[a0];
        const float4 Y = *(const float4*)&nsy[a0];
        const float4 Z = *(const float4*)&nsz[a0];
        const v2f Xl = {X.x, X.y}, Xh = {X.z, X.w};
        const v2f Yl = {Y.x, Y.y}, Yh = {Y.z, Y.w};
        const v2f Zl = {Z.x, Z.y}, Zh = {Z.z, Z.w};
        const v2f sAl = pk_s2(qxA2, qyA2, qzA2, Xl, Yl, Zl);
        const v2f sAh = pk_s2(qxA2, qyA2, qzA2, Xh, Yh, Zh);
        const v2f sBl = pk_s2(qxB2, qyB2, qzB2, Xl, Yl, Zl);
        const v2f sBh = pk_s2(qxB2, qyB2, qzB2, Xh, Yh, Zh);
        mA0 = fminf(mA0, fminf(sAl.x, sAh.x));
        mA1 = fminf(mA1, fminf(sAl.y, sAh.y));
        mB0 = fminf(mB0, fminf(sBl.x, sBh.x));
        mB1 = fminf(mB1, fminf(sBl.y, sBh.y));
    }
    unsigned int mnA = __float_as_uint(fminf(mA0, mA1));
    unsigned int mnB = __float_as_uint(fminf(mB0, mB1));
    bitonic_sort64_u32(mnA, lane);
    bitonic_sort64_u32(mnB, lane);
    // 32nd-smallest lane-min in fma-space, +64 ulp-bits: provably covers every
    // reference-top-32 atom (fma vs exact-sequence differ <= ~5 bit-steps through
    // the witness chain). Ts=inf (degenerate masks) floods -> cnt>CAP -> fallback.
    const unsigned int STA = __shfl(mnA, 31) + 64u;
    const unsigned int STB = __shfl(mnB, 31) + 64u;

    // ---- pass 2: ballot-collect candidate indices (idx only; keys recomputed) ----
    unsigned int* cbA = reinterpret_cast<unsigned int*>(pool) + wv * CAP;
    unsigned int* cbB = reinterpret_cast<unsigned int*>(pool) + (WAVES + wv) * CAP;
    const unsigned long long lt = (1ull << lane) - 1ull;
    int cntA = 0, cntB = 0;
    auto collect = [&](float s, int idx, unsigned int ST, int& cnt,
                       unsigned int* cb) {
        const bool p = __float_as_uint(s) <= ST;
        const unsigned long long m = __ballot(p);
        if (p) {
            const int sl = cnt + __popcll(m & lt);
            if (sl < CAP) cb[sl] = (unsigned int)idx;
        }
        cnt += __popcll(m);
    };
    for (int i = 0; i < N_ / 256; ++i) {
        const int a0 = i * 256 + lane * 4;
        const float4 X = *(const float4*)&nsx[a0];
        const float4 Y = *(const float4*)&nsy[a0];
        const float4 Z = *(const float4*)&nsz[a0];
        const v2f Xl = {X.x, X.y}, Xh = {X.z, X.w};
        const v2f Yl = {Y.x, Y.y}, Yh = {Y.z, Y.w};
        const v2f Zl = {Z.x, Z.y}, Zh = {Z.z, Z.w};
        const v2f sAl = pk_s2(qxA2, qyA2, qzA2, Xl, Yl, Zl);
        const v2f sAh = pk_s2(qxA2, qyA2, qzA2, Xh, Yh, Zh);
        const v2f sBl = pk_s2(qxB2, qyB2, qzB2, Xl, Yl, Zl);
        const v2f sBh = pk_s2(qxB2, qyB2, qzB2, Xh, Yh, Zh);
        collect(sAl.x, a0 + 0, STA, cntA, cbA);
        collect(sAl.y, a0 + 1, STA, cntA, cbA);
        collect(sAh.x, a0 + 2, STA, cntA, cbA);
        collect(sAh.y, a0 + 3, STA, cntA, cbA);
        collect(sBl.x, a0 + 0, STB, cntB, cbB);
        collect(sBl.y, a0 + 1, STB, cntB, cbB);
        collect(sBh.x, a0 + 2, STB, cntB, cbB);
        collect(sBh.y, a0 + 3, STB, cntB, cbB);
    }

    // ---- pass 3 / fallback: exact (d_bits, idx) top-32 per query ----
    auto select_top32 = [&](const unsigned int* cbuf, int cnt,
                            float qx, float qy, float qz) -> unsigned long long {
        if (cnt <= CAP) {
            unsigned long long best = ~0ull;
            const int nch = (cnt + 63) >> 6;
            for (int c = 0; c < nch; ++c) {
                const int slot = c * 64 + lane;
                unsigned long long v = ~0ull;
                if (slot < cnt) {
                    const int id = (int)cbuf[slot];
                    // exact reference path (negation is exact: q + (-c) == q - c)
                    const float dx = __fadd_rn(qx, nsx[id]);
                    const float dy = __fadd_rn(qy, nsy[id]);
                    const float dz = __fadd_rn(qz, nsz[id]);
                    const float s = __fadd_rn(
                        __fadd_rn(__fmul_rn(dx, dx), __fmul_rn(dy, dy)),
                        __fmul_rn(dz, dz));
                    const float d = __fsqrt_rn(__fadd_rn(s, 1e-12f));
                    v = ((unsigned long long)__float_as_uint(d) << 32)
                      | (unsigned int)id;
                }
                bitonic_sort64_u64(v, lane);
                if (c == 0) best = v;
                else        merge64_u64(best, v, lane);
            }
            return best;
        }
        // fallback (pathological masks/ties): exact streaming insertion
        unsigned long long key = ~0ull;
        for (int base = 0; base < N_; base += 64) {
            const int a = base + lane;
            const float dx = __fadd_rn(qx, nsx[a]);
            const float dy = __fadd_rn(qy, nsy[a]);
            const float dz = __fadd_rn(qz, nsz[a]);
            const float s = __fadd_rn(
                __fadd_rn(__fmul_rn(dx, dx), __fmul_rn(dy, dy)),
                __fmul_rn(dz, dz));
            const float d = __fsqrt_rn(__fadd_rn(s, 1e-12f));
            unsigned long long cand =
                ((unsigned long long)__float_as_uint(d) << 32) | (unsigned int)a;
            const unsigned long long T = __shfl(key, 31);
            unsigned long long m = __ballot(cand < T);
            while (m) {
                const int src = __ffsll(m) - 1;
                m &= m - 1;
                const unsigned long long nk = __shfl(cand, src);
                const unsigned long long up = __shfl_up(key, 1);
                if (lane < K_) {
                    const unsigned long long repl =
                        (lane == 0) ? nk : (up <= nk ? nk : up);
                    key = (key <= nk) ? key : repl;
                }
            }
        }
        return key;
    };

    const unsigned long long keyA = select_top32(cbA, cntA, qxA, qyA, qzA);
    const unsigned long long keyB = select_top32(cbB, cntB, qxB, qyB, qzB);

    const size_t BQK = (size_t)B_ * Q_ * K_;
    float* out_feat = out;
    float* out_mask = out + BQK * (size_t)F_;
    float* out_idx  = out_mask + BQK;
    float* out_dist = out_idx + BQK;

    const bool qmA = query_mask[qA] != 0;
    const bool qmB = query_mask[qB] != 0;

    // scalar outputs (no stage pool needed) before the overlay barrier
    if (lane < K_) {
        {
            const float d = __uint_as_float((unsigned int)(keyA >> 32));
            const int  id = (int)(keyA & 0xFFFFFFFFull);
            const bool am = ((unsigned int)(keyA >> 32)) < 0x7F800000u;
            const bool nm = am && (d <= 5.0f) && qmA;
            const size_t o = (size_t)qA * K_ + lane;
            out_mask[o] = nm ? 1.0f : 0.0f;
            out_idx[o]  = am ? (float)id : -1.0f;
            out_dist[o] = nm ? d : 0.0f;
        }
        {
            const float d = __uint_as_float((unsigned int)(keyB >> 32));
            const int  id = (int)(keyB & 0xFFFFFFFFull);
            const bool am = ((unsigned int)(keyB >> 32)) < 0x7F800000u;
            const bool nm = am && (d <= 5.0f) && qmB;
            const size_t o = (size_t)qB * K_ + lane;
            out_mask[o] = nm ? 1.0f : 0.0f;
            out_idx[o]  = am ? (float)id : -1.0f;
            out_dist[o] = nm ? d : 0.0f;
        }
    }

    __syncthreads();   // all cand-buffer reads done before stage overlay

    // ---- feature build: NSLOT stage slots, 8 barrier rounds (2 per wave) ----
    auto build_and_store = [&](int q, unsigned long long key,
                               float qx, float qy, float qz, bool qm,
                               float* slotp) {
        const float d_l  = __uint_as_float((unsigned int)(key >> 32));
        const int   id_l = (int)(key & 0xFFFFFFFFull) & (N_ - 1);
        const bool  am_l = ((unsigned int)(key >> 32)) < 0x7F800000u;
        const bool  nm_l = am_l && (d_l <= 5.0f) && qm;

        if (lane < K_) {
            float* f = slotp + lane * F_;
            f[0] = nm_l ? __fadd_rn(qx, nsx[id_l]) : 0.0f;
            f[1] = nm_l ? __fadd_rn(qy, nsy[id_l]) : 0.0f;
            f[2] = nm_l ? __fadd_rn(qz, nsz[id_l]) : 0.0f;
            f[3] = nm_l ? radii[b * N_ + id_l] : 0.0f;

            const int t = atom_types[b * N_ + id_l];
            const float4* er4 = (const float4*)(embed + t * E_);
            #pragma unroll
            for (int e = 0; e < E_ / 4; ++e) {
                const float4 v = er4[e];
                f[4 + e * 4 + 0] = nm_l ? v.x : 0.0f;
                f[4 + e * 4 + 1] = nm_l ? v.y : 0.0f;
                f[4 + e * 4 + 2] = nm_l ? v.z : 0.0f;
                f[4 + e * 4 + 3] = nm_l ? v.w : 0.0f;
            }

            const float NG = -(float)(256.0 / 25.0);   // -RBF_GAMMA
            #pragma unroll
            for (int rr = 0; rr < R_; ++rr) {
                const float dd = __fsub_rn(d_l, centers[rr]);
                const float a2 = __fmul_rn(dd, dd);
                f[36 + rr] = nm_l ? expf(__fmul_rn(NG, a2)) : 0.0f;
            }
            f[52] = nm_l ? d_l : 0.0f;
        }
        // same-wave LDS in-order: copy sees this wave's writes without a barrier
        const float4* s4 = (const float4*)slotp;
        float4* d4 = (float4*)(out_feat + (size_t)q * (size_t)TILE);
        for (int t4 = lane; t4 < TILE / 4; t4 += 64) d4[t4] = s4[t4];
    };

    float* stagef = reinterpret_cast<float*>(pool);
    for (int r = 0; r < 8; ++r) {
        if ((wv >> 2) == (r & 3)) {
            float* slotp = stagef + (size_t)(wv & (NSLOT - 1)) * TILE;
            if (r < 4) build_and_store(qA, keyA, qxA, qyA, qzA, qmA, slotp);
            else       build_and_store(qB, keyB, qxB, qyB, qzB, qmB, slotp);
        }
        __syncthreads();
    }
}

extern "C" void kernel_launch(void* const* d_in, const int* in_sizes, int n_in,
                              void* d_out, int out_size, void* d_ws, size_t ws_size,
                              hipStream_t stream) {
    const float* coords     = (const float*)d_in[0];
    const int*   atom_types = (const int*)d_in[1];
    const float* radii      = (const float*)d_in[2];
    const float* qpts       = (const float*)d_in[3];
    const int*   atom_mask  = (const int*)d_in[4];
    const int*   query_mask = (const int*)d_in[5];
    const float* embed      = (const float*)d_in[6];
    const float* centers    = (const float*)d_in[7];

    dim3 grid((B_ * Q_) / QPB);
    dim3 block(THREADS);
    lfb_kernel<<<grid, block, 0, stream>>>(coords, atom_types, radii, qpts,
                                           atom_mask, query_mask, embed, centers,
                                           (float*)d_out);
}